// Round 7
// baseline (511.991 us; speedup 1.0000x reference)
//
#include <hip/hip_runtime.h>

#define BB 2
#define HH 1024
#define WW 1024
#define MU 5

// fused-pass tile geometry (78 staged tang cols for LDS margin)
#define TH 32
#define TW 64
#define SH (TH + 2 * MU)   // 42 staged rows
#define TCW 78             // tang staged cols: px w0-6 .. w0+71 (halo 6/8)
#define TST (TCW * 2)      // tang LDS row stride in floats (156)
#define SMS 81             // em LDS row stride (80 cols, odd stride -> conflict-free)
#define SVS 79             // V-result LDS row stride (odd -> conflict-free H reads)
#define LDSF (SH * TST + SH * SMS)   // 6552 + 3402 = 9954 floats = 39816 B

#define BAR_LINE 32        // 32 uints = 128 B per counter line

__device__ __forceinline__ float fast_rcp(float x) { return __builtin_amdgcn_rcpf(x); }
__device__ __forceinline__ float fast_rsq(float x) { return __builtin_amdgcn_rsqf(x); }

// ---------------------------------------------------------------------------
// Hierarchical grid barrier, ACQUIRE polls (R6 lesson: R5's RELAXED poll can
// lower to an L1-cacheable load -> stale spin -> valve -> container timeout.
// R4's flat barrier used ACQUIRE polls and was CORRECT, just contended; this
// keeps R4's proven poll semantics and only fixes contention: 8 groups x 128
// blocks on separate 128B lines (~0.13 polls/cy/line vs R4's ~1.3 on one).
// Last group-arriver forwards a token to the global line; 8th global arriver
// release-stores 8 per-group flags. Per-instance counters (no epochs),
// memset-zeroed each launch. Layout per instance k: lines [k*17+0..7] group
// counters, [k*17+8] global, [k*17+9..16] release flags. 3 instances=6528B.
// Valve: 1<<17 spins * ~0.43us ~= 56ms/barrier -> finite fail, no hang.
// ---------------------------------------------------------------------------
__device__ __forceinline__ void gridbar(unsigned* base, int k, int grp, int t)
{
    __syncthreads();               // all waves' stores issued & drained
    if (t == 0) {
        unsigned* gcnt = base + (k * 17 + grp) * BAR_LINE;
        unsigned* glob = base + (k * 17 + 8) * BAR_LINE;
        unsigned* rel  = base + (k * 17 + 9 + grp) * BAR_LINE;
        unsigned rv = __hip_atomic_fetch_add(gcnt, 1u, __ATOMIC_ACQ_REL,
                                             __HIP_MEMORY_SCOPE_AGENT);
        if (rv == 127u) {          // last arriver of this group
            unsigned gv = __hip_atomic_fetch_add(glob, 1u, __ATOMIC_ACQ_REL,
                                                 __HIP_MEMORY_SCOPE_AGENT);
            if (gv == 7u) {        // last group overall: release everyone
                #pragma unroll
                for (int x = 0; x < 8; ++x)
                    __hip_atomic_store(base + (k * 17 + 9 + x) * BAR_LINE, 1u,
                                       __ATOMIC_RELEASE, __HIP_MEMORY_SCOPE_AGENT);
            }
        }
        int spins = 0;
        while (__hip_atomic_load(rel, __ATOMIC_ACQUIRE,
                                 __HIP_MEMORY_SCOPE_AGENT) == 0u) {
            __builtin_amdgcn_s_sleep(16);
            if (++spins > (1 << 17)) break;   // safety valve (finite fail)
        }
    }
    __syncthreads();
}

// ---------------------------------------------------------------------------
// One ETF V+H pass (proven compute structure, bit-identical numerics; s2
// hoisted). Weight identity: (tanh(my-mx)+1)/2 == 1/(1 + em_y/em_x),
// em = exp(-2*mag/gmax). OOB: tang=0, em=1 (exact reference zero-pad).
// STAGE_EM: only pass 1 stages+exps the em tile. The sm region (floats
// 6552..9954) is never overwritten by sobel xs (2584), V/H results (sv ends
// at 5056), or tang staging (ends 6552), and the block's tile is persistent
// -> passes 2/3 reuse em: -840 stage iters and -840 __expf per block/pass.
// Verified in-situ R4: fused pass bodies produced absmax 0.00390625.
// ---------------------------------------------------------------------------
template <int PLANAR, int STAGE_EM>
__device__ __forceinline__ void etf_pass(
    float* __restrict__ lds,
    const float* __restrict__ tb,    // tin + 2*b*plane (interleaved)
    const float* __restrict__ mb,    // mag + b*plane (raw)
    float* __restrict__ o0,          // interleaved out, or planar plane 0
    float* __restrict__ o1,          // planar plane 1 (PLANAR only)
    float s2, int t, int w0, int h0)
{
    float* st  = lds;                 // staged tang, float2/px, row stride TST
    float* sm  = lds + SH * TST;      // staged em, row stride SMS
    float* sv0 = lds;                 // V results plane 0 (aliases st)
    float* sv1 = lds + TH * SVS;      // V results plane 1

    // ---- stage: tang 42x39 float4 (2px); em 42x20 float4 (4px) + exp
    const int NITER = STAGE_EM ? (SH * 39 + SH * 20) : (SH * 39);
    for (int i = t; i < NITER; i += 256) {
        if (!STAGE_EM || i < SH * 39) {
            int r = i / 39, c4 = i % 39;
            int g = h0 - MU + r;
            int gw = w0 - 6 + 2 * c4;                  // even -> 16B-aligned
            float4 v = make_float4(0.f, 0.f, 0.f, 0.f);
            if (g >= 0 && g < HH && gw >= 0 && gw < WW)
                v = *(const float4*)(tb + 2 * ((size_t)g * WW + gw));
            *(float4*)&st[r * TST + 4 * c4] = v;
        } else {
            int j = i - SH * 39;
            int r = j / 20, c4 = j % 20;
            int g = h0 - MU + r;
            int gw = w0 - 8 + 4 * c4;                  // mult of 4 -> 16B-aligned
            float4 v = make_float4(0.f, 0.f, 0.f, 0.f);   // mag=0 -> em=1
            if (g >= 0 && g < HH && gw >= 0 && gw < WW)
                v = *(const float4*)(mb + (size_t)g * WW + gw);
            float* dst = &sm[r * SMS + 4 * c4];
            dst[0] = __expf(-s2 * v.x);
            dst[1] = __expf(-s2 * v.y);
            dst[2] = __expf(-s2 * v.z);
            dst[3] = __expf(-s2 * v.w);
        }
    }
    __syncthreads();

    // ---- shared register window (reused by V then H phase)
    float r0a[21], r1a[21], rea[21];

    // ---- V phase: 234 threads = 78 cols x 3 row-strips {11,11,10}.
    // tang col c <-> px (w0-6+c) <-> em col (c+2).
    const int c = t % TCW;
    const int strip = t / TCW;
    const int vr0row = strip * 11;
    const int Rv = (strip == 2) ? 10 : 11;
    if (t < 3 * TCW) {
        #pragma unroll
        for (int j = 0; j < 21; ++j) {
            if (j < Rv + 10) {
                float2 v = *(const float2*)&st[(vr0row + j) * TST + 2 * c];
                r0a[j] = v.x; r1a[j] = v.y;
                rea[j] = sm[(vr0row + j) * SMS + c + 2];
            }
        }
    }
    __syncthreads();          // all st reads done; safe to overwrite via sv alias

    __builtin_amdgcn_s_setprio(1);
    if (t < 3 * TCW) {
        #pragma unroll
        for (int i = 0; i < 11; ++i) {
            if (i < Rv) {
                float tx0 = r0a[i + 5], tx1 = r1a[i + 5];
                float remx = fast_rcp(rea[i + 5]);
                float a0 = 0.f, a1 = 0.f;
                #pragma unroll
                for (int d = 0; d <= 2 * MU; ++d) {
                    float y0 = r0a[i + d], y1 = r1a[i + d], ey = rea[i + d];
                    float s = fast_rcp(fmaf(ey, remx, 1.f));    // (tanh(my-mx)+1)/2
                    float w = s * fmaf(tx0, y0, tx1 * y1);
                    a0 = fmaf(y0, w, a0);
                    a1 = fmaf(y1, w, a1);
                }
                float n2 = fmaf(a0, a0, a1 * a1);
                float inv = (n2 == 0.f) ? 1.f : fast_rsq(n2);
                sv0[(vr0row + i) * SVS + c] = a0 * inv;
                sv1[(vr0row + i) * SVS + c] = a1 * inv;
            }
        }
    }
    __builtin_amdgcn_s_setprio(0);
    __syncthreads();

    // ---- H phase: r = t&31, colgroup = t>>5 of 8 cols; center col of
    // output col (cg*8+k) is staged col (6+cg*8+k).
    const int r = t & 31;
    const int cg_ = t >> 5;
    const int cbase = 6 + cg_ * 8;
    #pragma unroll
    for (int j = 0; j < 18; ++j) {
        int sc = cbase - 5 + j;              // 1..74: always in [0,TCW)
        r0a[j] = sv0[r * SVS + sc];
        r1a[j] = sv1[r * SVS + sc];
        rea[j] = sm[(r + MU) * SMS + sc + 2];
    }
    __syncthreads();          // all sv reads done; safe to overwrite below

    __builtin_amdgcn_s_setprio(1);
    #pragma unroll
    for (int k = 0; k < 8; ++k) {
        float tx0 = r0a[k + 5], tx1 = r1a[k + 5];
        float remx = fast_rcp(rea[k + 5]);
        float a0 = 0.f, a1 = 0.f;
        #pragma unroll
        for (int d = 0; d <= 2 * MU; ++d) {
            float y0 = r0a[k + d], y1 = r1a[k + d], ey = rea[k + d];
            float s = fast_rcp(fmaf(ey, remx, 1.f));
            float w = s * fmaf(tx0, y0, tx1 * y1);
            a0 = fmaf(y0, w, a0);
            a1 = fmaf(y1, w, a1);
        }
        float n2 = fmaf(a0, a0, a1 * a1);
        float inv = (n2 == 0.f) ? 1.f : fast_rsq(n2);
        sv0[r * SVS + cbase + k] = a0 * inv;    // write to LDS (post-barrier)
        sv1[r * SVS + cbase + k] = a1 * inv;
    }
    __builtin_amdgcn_s_setprio(0);
    __syncthreads();

    // ---- coalesced global writeout (lanes along cols)
    #pragma unroll
    for (int m = 0; m < 8; ++m) {
        int px = t + 256 * m;
        int rr = px >> 6, cc = px & 63;
        float v0 = sv0[rr * SVS + 6 + cc];
        float v1 = sv1[rr * SVS + 6 + cc];
        size_t gi = (size_t)(h0 + rr) * WW + (w0 + cc);
        if (PLANAR) {
            o0[gi] = v0;
            o1[gi] = v1;
        } else {
            *(float2*)&o0[2 * gi] = make_float2(v0, v1);
        }
    }
}

// ---------------------------------------------------------------------------
// MEGA-KERNEL: sobel -> gridbar -> gmax(once) -> pass1(em) -> gridbar ->
// pass2 -> gridbar -> pass3. Residency proof: LDS 39936B x4 = 159744 <
// 160KiB; __launch_bounds__(256,4) caps VGPR -> 4 blocks/CU; 1024 = 256x4.
// ---------------------------------------------------------------------------
__global__ __launch_bounds__(256, 4) void etf_all(
    const float* __restrict__ x,
    float* __restrict__ tfA,
    float* __restrict__ tfB,
    float* __restrict__ mag,
    float* __restrict__ block_max,
    unsigned* __restrict__ bar,
    float* __restrict__ out)
{
    __shared__ float lds[LDSF];
    __shared__ float smax[4];

    const int t = threadIdx.x;
    const int lin0 = blockIdx.x;
    const int grp = lin0 & 7;      // barrier group (128 blocks each)
    // XCD-aware swizzle (measured neutral; kept for slab locality; bijective)
    const int lin = (lin0 & 7) * 128 + (lin0 >> 3);
    const int w0 = (lin & 15) * TW;
    const int h0 = ((lin >> 4) & 31) * TH;
    const int b  = lin >> 9;
    const size_t plane = (size_t)HH * WW;

    // ---------------- Phase S: sobel + init tangent on this 32x64 tile ----
    {
        float* xs = lds;                       // 34 rows x stride 76
        const float* xb = x + (size_t)b * plane;
        for (int i = t; i < 34 * 18; i += 256) {
            int r = i / 18, c4 = i % 18;
            int g = h0 - 1 + r;
            int gw = w0 - 4 + 4 * c4;
            float4 v = make_float4(0.f, 0.f, 0.f, 0.f);
            if (g >= 0 && g < HH && gw >= 0 && gw < WW)
                v = *(const float4*)(xb + (size_t)g * WW + gw);
            *(float4*)&xs[r * 76 + 4 * c4] = v;
        }
        __syncthreads();

        float lmax = 0.f;
        const int cc = t & 63;
        const int rr = t >> 6;
        const int c = cc + 4;
        float* mb_w = mag + (size_t)b * plane;
        float2* tA2 = (float2*)(tfA + 2 * (size_t)b * plane);
        #pragma unroll
        for (int k = 0; k < 8; ++k) {
            int row = rr * 8 + k;
            const float* rT = &xs[row * 76];
            const float* rM = rT + 76;
            const float* rB = rM + 76;
            float tl = rT[c - 1], tc = rT[c], tr = rT[c + 1];
            float ml = rM[c - 1],             mr = rM[c + 1];
            float bl = rB[c - 1], bc = rB[c], br = rB[c + 1];
            float s0 = (bl - tl) + 2.f * (bc - tc) + (br - tr);   // k
            float s1 = (tr - tl) + 2.f * (mr - ml) + (br - bl);   // k^T
            float m = sqrtf(fmaf(s0, s0, s1 * s1));
            float inv = (m == 0.f) ? 1.f : fast_rcp(m);
            size_t gi = (size_t)(h0 + row) * WW + (w0 + cc);
            mb_w[gi] = m;
            tA2[gi] = make_float2(-s1 * inv, s0 * inv);
            lmax = fmaxf(lmax, m);
        }
        #pragma unroll
        for (int off = 32; off; off >>= 1) lmax = fmaxf(lmax, __shfl_down(lmax, off, 64));
        if ((t & 63) == 0) smax[t >> 6] = lmax;
        __syncthreads();
        if (t == 0)
            block_max[lin0] = fmaxf(fmaxf(smax[0], smax[1]), fmaxf(smax[2], smax[3]));
    }
    gridbar(bar, 0, grp, t);

    // ---------------- gmax reduce ONCE; s2 persists across iterations ------
    float s2;
    {
        float m = fmaxf(fmaxf(block_max[t], block_max[t + 256]),
                        fmaxf(block_max[t + 512], block_max[t + 768]));
        #pragma unroll
        for (int off = 32; off; off >>= 1) m = fmaxf(m, __shfl_down(m, off, 64));
        if ((t & 63) == 0) smax[t >> 6] = m;
        __syncthreads();
        const float gm = fmaxf(fmaxf(smax[0], smax[1]), fmaxf(smax[2], smax[3]));
        s2 = 2.f * fast_rcp(gm);
    }
    __syncthreads();   // smax reads done before any LDS reuse below

    const float* mb = mag + (size_t)b * plane;
    float* tA = tfA + 2 * (size_t)b * plane;
    float* tB = tfB + 2 * (size_t)b * plane;

    // ---------------- 3 ETF iterations, ping-pong through global -----------
    etf_pass<0, 1>(lds, tA, mb, tB, nullptr, s2, t, w0, h0);
    gridbar(bar, 1, grp, t);
    etf_pass<0, 0>(lds, tB, mb, tA, nullptr, s2, t, w0, h0);
    gridbar(bar, 2, grp, t);
    etf_pass<1, 0>(lds, tA, mb,
                   out + (size_t)(2 * b) * plane,
                   out + (size_t)(2 * b + 1) * plane,
                   s2, t, w0, h0);
}

extern "C" void kernel_launch(void* const* d_in, const int* in_sizes, int n_in,
                              void* d_out, int out_size, void* d_ws, size_t ws_size,
                              hipStream_t stream)
{
    const float* x = (const float*)d_in[0];   // (2,1,1024,1024) fp32
    char* ws = (char*)d_ws;
    const size_t plane = (size_t)HH * WW;

    float* tfA     = (float*)ws;                                        // 16 MB interleaved
    float* tfB     = (float*)(ws + sizeof(float) * BB * 2 * plane);     // 16 MB interleaved
    float* mg      = (float*)(ws + sizeof(float) * BB * 4 * plane);     // 8 MB raw
    float* bmax    = (float*)(ws + sizeof(float) * BB * 5 * plane);     // 1024 floats
    unsigned* bar  = (unsigned*)(ws + sizeof(float) * (BB * 5 * plane + 1024));

    hipMemsetAsync(bar, 0, 8192, stream);     // all barrier lines := 0 each launch

    etf_all<<<dim3(1024), dim3(256), 0, stream>>>(x, tfA, tfB, mg, bmax, bar,
                                                  (float*)d_out);
}

// Round 8
// 139.557 us; speedup vs baseline: 3.6687x; 3.6687x over previous
//
#include <hip/hip_runtime.h>

#define BB 2
#define HH 1024
#define WW 1024
#define MU 5

// fused-pass tile geometry (78 staged tang cols; em read from L2, not LDS)
#define TH 32
#define TW 64
#define SH (TH + 2 * MU)   // 42 staged rows
#define TCW 78             // tang staged cols: px w0-6 .. w0+71
#define TST (TCW * 2)      // tang LDS row stride in floats (156)
#define SVS 79             // V-result LDS row stride (odd -> conflict-free H reads)
#define LDSF (SH * TST)    // 6552 floats = 26208 B -> 26624 B granule

__device__ __forceinline__ float fast_rcp(float x) { return __builtin_amdgcn_rcpf(x); }
__device__ __forceinline__ float fast_rsq(float x) { return __builtin_amdgcn_rsqf(x); }

__device__ __forceinline__ float magat(const float* __restrict__ mb, int g, int gw)
{
    return (g >= 0 && g < HH && gw >= 0 && gw < WW)
         ? mb[(size_t)g * WW + gw] : 0.f;     // OOB mag=0 -> em=1 (ref zero-pad)
}

// ---------------------------------------------------------------------------
// Kernel 1: Sobel + init tangent (interleaved (B,H,W,2)) + raw mag + block
// max. (Proven R1/R3 version, 131us baseline.)
// ---------------------------------------------------------------------------
#define SR 8
__global__ __launch_bounds__(256) void sobel_init(
    const float* __restrict__ x,
    float* __restrict__ tf,          // (B,H,W,2) interleaved
    float* __restrict__ mag,         // (B,H,W) raw
    float* __restrict__ block_max)   // 1024
{
    __shared__ float xs[SR + 2][264];
    const int t = threadIdx.x;
    const int w0 = blockIdx.x * 256;
    const int h0 = blockIdx.y * SR;
    const int b = blockIdx.z;
    const size_t plane = (size_t)HH * WW;
    const float* xb = x + (size_t)b * plane;

    for (int i = t; i < (SR + 2) * 66; i += 256) {
        int r = i / 66, c4 = i % 66;
        int g = h0 - 1 + r;
        int gw = w0 - 4 + 4 * c4;
        float4 v = make_float4(0.f, 0.f, 0.f, 0.f);
        if (g >= 0 && g < HH && gw >= 0 && gw < WW)
            v = *(const float4*)(xb + (size_t)g * WW + gw);
        *(float4*)&xs[r][4 * c4] = v;
    }
    __syncthreads();

    float lmax = 0.f;
    const int c = 4 + t;
    #pragma unroll
    for (int k = 0; k < SR; ++k) {
        const float* rT = xs[k], * rM = xs[k + 1], * rB = xs[k + 2];
        float tl = rT[c - 1], tc = rT[c], tr = rT[c + 1];
        float ml = rM[c - 1],             mr = rM[c + 1];
        float bl = rB[c - 1], bc = rB[c], br = rB[c + 1];
        float s0 = (bl - tl) + 2.f * (bc - tc) + (br - tr);   // k
        float s1 = (tr - tl) + 2.f * (mr - ml) + (br - bl);   // k^T
        float m = sqrtf(fmaf(s0, s0, s1 * s1));
        float inv = (m == 0.f) ? 1.f : fast_rcp(m);
        size_t gi = (size_t)(h0 + k) * WW + (w0 + t);
        mag[(size_t)b * plane + gi] = m;
        ((float2*)tf)[(size_t)b * plane + gi] = make_float2(-s1 * inv, s0 * inv);
        lmax = fmaxf(lmax, m);
    }

    #pragma unroll
    for (int off = 32; off; off >>= 1) lmax = fmaxf(lmax, __shfl_down(lmax, off, 64));
    __shared__ float smax[4];
    if ((t & 63) == 0) smax[t >> 6] = lmax;
    __syncthreads();
    if (t == 0)
        block_max[(blockIdx.z * 128 + blockIdx.y) * 4 + blockIdx.x] =
            fmaxf(fmaxf(smax[0], smax[1]), fmaxf(smax[2], smax[3]));
}

// ---------------------------------------------------------------------------
// Kernel 2: FUSED V+H ETF pass. R7 change (lesson from fused-kernel PMC:
// per-pass HBM ~13MB / VALU ~6us of a 37us pass -> latency-bound at 4
// blocks/CU): DELETE the em LDS plane; read mag straight from global (L2-hot
// slab with the XCD swizzle) in the V/H read phases and __expf there.
// Bit-identical numerics: same fp32 mag words, same expf inputs, same FMA
// chains (78-col geometry proven bit-exact in R4/R6 fused runs).
// LDS 39936 -> 26624 B (6 blocks/CU by LDS); launch_bounds(256,5) caps
// VGPR<=102 -> 5 blocks/CU net, +25% TLP; stage loop -34% iterations.
// Weight identity: (tanh(my-mx)+1)/2 == 1/(1 + em_y/em_x), em=exp(-2mag/gm).
// ---------------------------------------------------------------------------
template <int PLANAR_OUT>
__global__ __launch_bounds__(256, 5) void etf_vh(
    const float* __restrict__ tin,   // (B,H,W,2) interleaved
    float* __restrict__ tout,        // interleaved, or planar (B,2,H,W)
    const float* __restrict__ mag,   // (B,H,W) RAW
    const float* __restrict__ block_max)
{
    __shared__ float lds[LDSF];      // 26208 B
    __shared__ float smax[4];
    float* st  = lds;                 // staged tang, float2/px, row stride TST
    float* sv0 = lds;                 // V results plane 0 (aliases st)
    float* sv1 = lds + TH * SVS;      // V results plane 1

    const int t = threadIdx.x;

    // XCD-aware swizzle (keeps tang+mag slab L2-resident per XCD; mag
    // residency now matters every pass). Bijective: 1024 % 8 == 0.
    int lin = blockIdx.x + 16 * blockIdx.y + 512 * blockIdx.z;   // grid 16x32xBB
    lin = (lin & 7) * ((16 * 32 * BB) >> 3) + (lin >> 3);
    const int w0 = (lin & 15) * TW;
    const int h0 = ((lin >> 4) & 31) * TH;
    const int b  = lin >> 9;

    const size_t plane = (size_t)HH * WW;
    const float* tb = tin + 2 * (size_t)b * plane;
    const float* mb = mag + (size_t)b * plane;

    // ---- prologue: redundant gmax reduce (proven cheap; L2-hot)
    {
        float m = fmaxf(fmaxf(block_max[t], block_max[t + 256]),
                        fmaxf(block_max[t + 512], block_max[t + 768]));
        #pragma unroll
        for (int off = 32; off; off >>= 1) m = fmaxf(m, __shfl_down(m, off, 64));
        if ((t & 63) == 0) smax[t >> 6] = m;
    }
    __syncthreads();
    const float gm = fmaxf(fmaxf(smax[0], smax[1]), fmaxf(smax[2], smax[3]));
    const float s2 = 2.f * fast_rcp(gm);

    // ---- stage: tang only, 42 rows x 39 float4 (2px) chunks
    for (int i = t; i < SH * 39; i += 256) {
        int r = i / 39, c4 = i % 39;
        int g = h0 - MU + r;
        int gw = w0 - 6 + 2 * c4;                  // even -> 16B-aligned
        float4 v = make_float4(0.f, 0.f, 0.f, 0.f);
        if (g >= 0 && g < HH && gw >= 0 && gw < WW)
            v = *(const float4*)(tb + 2 * ((size_t)g * WW + gw));
        *(float4*)&st[r * TST + 4 * c4] = v;
    }
    __syncthreads();

    // ---- shared register window (reused by V then H phase)
    float r0a[21], r1a[21], rea[21];

    // ---- V phase: 234 threads = 78 cols x 3 row-strips {11,11,10}.
    // tang col c <-> px (w0-6+c); em from global mag (lane-coalesced cols).
    const int c = t % TCW;
    const int strip = t / TCW;
    const int vr0row = strip * 11;
    const int Rv = (strip == 2) ? 10 : 11;
    if (t < 3 * TCW) {
        #pragma unroll
        for (int j = 0; j < 21; ++j) {
            if (j < Rv + 10) {
                float2 v = *(const float2*)&st[(vr0row + j) * TST + 2 * c];
                r0a[j] = v.x; r1a[j] = v.y;
                rea[j] = __expf(-s2 * magat(mb, h0 - MU + vr0row + j, w0 - 6 + c));
            }
        }
    }
    __syncthreads();          // all st reads done; safe to overwrite via sv alias

    __builtin_amdgcn_s_setprio(1);
    if (t < 3 * TCW) {
        #pragma unroll
        for (int i = 0; i < 11; ++i) {
            if (i < Rv) {
                float tx0 = r0a[i + 5], tx1 = r1a[i + 5];
                float remx = fast_rcp(rea[i + 5]);
                float a0 = 0.f, a1 = 0.f;
                #pragma unroll
                for (int d = 0; d <= 2 * MU; ++d) {
                    float y0 = r0a[i + d], y1 = r1a[i + d], ey = rea[i + d];
                    float s = fast_rcp(fmaf(ey, remx, 1.f));    // (tanh(my-mx)+1)/2
                    float w = s * fmaf(tx0, y0, tx1 * y1);
                    a0 = fmaf(y0, w, a0);
                    a1 = fmaf(y1, w, a1);
                }
                float n2 = fmaf(a0, a0, a1 * a1);
                float inv = (n2 == 0.f) ? 1.f : fast_rsq(n2);
                sv0[(vr0row + i) * SVS + c] = a0 * inv;
                sv1[(vr0row + i) * SVS + c] = a1 * inv;
            }
        }
    }
    __builtin_amdgcn_s_setprio(0);
    __syncthreads();

    // ---- H phase: r = t&31, colgroup = t>>5 of 8 cols; center staged col
    // of output col (cg*8+k) is (6+cg*8+k). em col for window j: w0+cg*8-5+j.
    const int r = t & 31;
    const int cg_ = t >> 5;
    const int cbase = 6 + cg_ * 8;
    #pragma unroll
    for (int j = 0; j < 18; ++j) {
        int sc = cbase - 5 + j;              // 1..74: always in [0,TCW)
        r0a[j] = sv0[r * SVS + sc];
        r1a[j] = sv1[r * SVS + sc];
        rea[j] = __expf(-s2 * magat(mb, h0 + r, w0 + cg_ * 8 - 5 + j));
    }
    __syncthreads();          // all sv reads done; safe to overwrite below

    __builtin_amdgcn_s_setprio(1);
    #pragma unroll
    for (int k = 0; k < 8; ++k) {
        float tx0 = r0a[k + 5], tx1 = r1a[k + 5];
        float remx = fast_rcp(rea[k + 5]);
        float a0 = 0.f, a1 = 0.f;
        #pragma unroll
        for (int d = 0; d <= 2 * MU; ++d) {
            float y0 = r0a[k + d], y1 = r1a[k + d], ey = rea[k + d];
            float s = fast_rcp(fmaf(ey, remx, 1.f));
            float w = s * fmaf(tx0, y0, tx1 * y1);
            a0 = fmaf(y0, w, a0);
            a1 = fmaf(y1, w, a1);
        }
        float n2 = fmaf(a0, a0, a1 * a1);
        float inv = (n2 == 0.f) ? 1.f : fast_rsq(n2);
        sv0[r * SVS + cbase + k] = a0 * inv;    // write to LDS (post-barrier)
        sv1[r * SVS + cbase + k] = a1 * inv;
    }
    __builtin_amdgcn_s_setprio(0);
    __syncthreads();

    // ---- coalesced global writeout (lanes along cols)
    #pragma unroll
    for (int m = 0; m < 8; ++m) {
        int px = t + 256 * m;
        int rr = px >> 6, cc = px & 63;
        float v0 = sv0[rr * SVS + 6 + cc];
        float v1 = sv1[rr * SVS + 6 + cc];
        size_t gi = (size_t)(h0 + rr) * WW + (w0 + cc);
        if (PLANAR_OUT) {
            tout[(size_t)(2 * b)     * plane + gi] = v0;
            tout[(size_t)(2 * b + 1) * plane + gi] = v1;
        } else {
            *(float2*)&tout[2 * ((size_t)b * plane + gi)] = make_float2(v0, v1);
        }
    }
}

extern "C" void kernel_launch(void* const* d_in, const int* in_sizes, int n_in,
                              void* d_out, int out_size, void* d_ws, size_t ws_size,
                              hipStream_t stream)
{
    const float* x = (const float*)d_in[0];   // (2,1,1024,1024) fp32
    char* ws = (char*)d_ws;
    const size_t plane = (size_t)HH * WW;

    float* tfA  = (float*)ws;                                           // 16 MB interleaved
    float* tfB  = (float*)(ws + sizeof(float) * BB * 2 * plane);        // 16 MB interleaved
    float* mag  = (float*)(ws + sizeof(float) * BB * 4 * plane);        // 8 MB raw
    float* block_max = (float*)(ws + sizeof(float) * BB * 5 * plane);   // 1024 floats

    sobel_init<<<dim3(4, 128, BB), 256, 0, stream>>>(x, tfA, mag, block_max);

    dim3 g(WW / TW, HH / TH, BB);
    etf_vh<0><<<g, 256, 0, stream>>>(tfA, tfB, mag, block_max);
    etf_vh<0><<<g, 256, 0, stream>>>(tfB, tfA, mag, block_max);
    etf_vh<1><<<g, 256, 0, stream>>>(tfA, (float*)d_out, mag, block_max);
}

// Round 9
// 132.719 us; speedup vs baseline: 3.8577x; 1.0515x over previous
//
#include <hip/hip_runtime.h>

#define BB 2
#define HH 1024
#define WW 1024
#define MU 5

// fused-pass tile geometry (exact 131us-proven baseline geometry)
#define TH 32
#define TW 64
#define SH (TH + 2 * MU)   // 42 staged rows
#define SCW 80             // staged cols = TW + 16 (8-col halo each side)
#define SMS 83             // em LDS row stride (odd -> conflict-free H reads)
#define SVS 81             // V-result LDS row stride (odd -> conflict-free H reads)

__device__ __forceinline__ float fast_rcp(float x) { return __builtin_amdgcn_rcpf(x); }
__device__ __forceinline__ float fast_rsq(float x) { return __builtin_amdgcn_rsqf(x); }

// ---------------------------------------------------------------------------
// Kernel 1: Sobel + init tangent (interleaved (B,H,W,2)) + raw mag + block
// max. (Proven baseline version.)
// ---------------------------------------------------------------------------
#define SR 8
__global__ __launch_bounds__(256) void sobel_init(
    const float* __restrict__ x,
    float* __restrict__ tf,          // (B,H,W,2) interleaved
    float* __restrict__ mag,         // (B,H,W) raw
    float* __restrict__ block_max)   // 1024
{
    __shared__ float xs[SR + 2][264];
    const int t = threadIdx.x;
    const int w0 = blockIdx.x * 256;
    const int h0 = blockIdx.y * SR;
    const int b = blockIdx.z;
    const size_t plane = (size_t)HH * WW;
    const float* xb = x + (size_t)b * plane;

    for (int i = t; i < (SR + 2) * 66; i += 256) {
        int r = i / 66, c4 = i % 66;
        int g = h0 - 1 + r;
        int gw = w0 - 4 + 4 * c4;
        float4 v = make_float4(0.f, 0.f, 0.f, 0.f);
        if (g >= 0 && g < HH && gw >= 0 && gw < WW)
            v = *(const float4*)(xb + (size_t)g * WW + gw);
        *(float4*)&xs[r][4 * c4] = v;
    }
    __syncthreads();

    float lmax = 0.f;
    const int c = 4 + t;
    #pragma unroll
    for (int k = 0; k < SR; ++k) {
        const float* rT = xs[k], * rM = xs[k + 1], * rB = xs[k + 2];
        float tl = rT[c - 1], tc = rT[c], tr = rT[c + 1];
        float ml = rM[c - 1],             mr = rM[c + 1];
        float bl = rB[c - 1], bc = rB[c], br = rB[c + 1];
        float s0 = (bl - tl) + 2.f * (bc - tc) + (br - tr);   // k
        float s1 = (tr - tl) + 2.f * (mr - ml) + (br - bl);   // k^T
        float m = sqrtf(fmaf(s0, s0, s1 * s1));
        float inv = (m == 0.f) ? 1.f : fast_rcp(m);
        size_t gi = (size_t)(h0 + k) * WW + (w0 + t);
        mag[(size_t)b * plane + gi] = m;
        ((float2*)tf)[(size_t)b * plane + gi] = make_float2(-s1 * inv, s0 * inv);
        lmax = fmaxf(lmax, m);
    }

    #pragma unroll
    for (int off = 32; off; off >>= 1) lmax = fmaxf(lmax, __shfl_down(lmax, off, 64));
    __shared__ float smax[4];
    if ((t & 63) == 0) smax[t >> 6] = lmax;
    __syncthreads();
    if (t == 0)
        block_max[(blockIdx.z * 128 + blockIdx.y) * 4 + blockIdx.x] =
            fmaxf(fmaxf(smax[0], smax[1]), fmaxf(smax[2], smax[3]));
}

// ---------------------------------------------------------------------------
// Kernel 1.5 (R8 new): gmax reduce + IN-PLACE mag -> em = exp(-2*mag/gmax).
// R7 evidence: ~2.8x expf count moved total time +8.5us -> each pass carries
// ~3-5us of v_exp_f32 (quarter-width trans unit). Baseline recomputes the
// SAME 8MB em field 3x; this computes it once. In-place is replay-safe
// (sobel rewrites mag every launch). Same reduce code as the old prologue
// -> same gm bits -> same s2 -> bit-identical em.
// 2048 blocks x 256 thr x 1 float4 = 2M px exactly.
// ---------------------------------------------------------------------------
__global__ __launch_bounds__(256) void em_prep(
    float* __restrict__ mag, const float* __restrict__ block_max)
{
    __shared__ float smax[4];
    const int t = threadIdx.x;
    float m = fmaxf(fmaxf(block_max[t], block_max[t + 256]),
                    fmaxf(block_max[t + 512], block_max[t + 768]));
    #pragma unroll
    for (int off = 32; off; off >>= 1) m = fmaxf(m, __shfl_down(m, off, 64));
    if ((t & 63) == 0) smax[t >> 6] = m;
    __syncthreads();
    const float gm = fmaxf(fmaxf(smax[0], smax[1]), fmaxf(smax[2], smax[3]));
    const float s2 = 2.f * fast_rcp(gm);

    const size_t i4 = (size_t)blockIdx.x * 256 + t;   // float4 index
    float4 v = ((const float4*)mag)[i4];
    v.x = __expf(-s2 * v.x);
    v.y = __expf(-s2 * v.y);
    v.z = __expf(-s2 * v.z);
    v.w = __expf(-s2 * v.w);
    ((float4*)mag)[i4] = v;
}

// ---------------------------------------------------------------------------
// Kernel 2: FUSED V+H ETF pass — exact proven-131us compute structure, now
// expf-free: em staged by pure float4 copy from the precomputed em buffer
// (OOB default 1.0 = exp(0), exact reference zero-pad semantics), and the
// per-pass gmax prologue is deleted (no s2 needed).
// Weight identity: (tanh(my-mx)+1)/2 == 1/(1 + em_y/em_x).
// LDS 40824 B -> 4 blocks/CU (unchanged from baseline).
// ---------------------------------------------------------------------------
template <int PLANAR_OUT>
__global__ __launch_bounds__(256, 4) void etf_vh(
    const float* __restrict__ tin,   // (B,H,W,2) interleaved
    float* __restrict__ tout,        // interleaved, or planar (B,2,H,W)
    const float* __restrict__ em)    // (B,H,W) PRECOMPUTED em
{
    __shared__ float lds[SH * SCW * 2 + SH * SMS];   // 40824 B
    float* st  = lds;                 // staged tang, float2/px, row stride 160 floats
    float* sm  = lds + SH * SCW * 2;  // staged em, row stride SMS
    float* sv0 = lds;                 // V results plane 0 (aliases st)
    float* sv1 = lds + TH * SVS;      // V results plane 1

    const int t = threadIdx.x;

    // XCD-aware swizzle (proven neutral; keeps per-XCD slab L2-resident)
    int lin = blockIdx.x + 16 * blockIdx.y + 512 * blockIdx.z;   // grid 16x32xBB
    lin = (lin & 7) * ((16 * 32 * BB) >> 3) + (lin >> 3);
    const int w0 = (lin & 15) * TW;
    const int h0 = ((lin >> 4) & 31) * TH;
    const int b  = lin >> 9;

    const size_t plane = (size_t)HH * WW;
    const float* tb = tin + 2 * (size_t)b * plane;
    const float* mb = em + (size_t)b * plane;

    // ---- stage: tang 42x40 float4 (2px) chunks; em 42x20 float4 (4px) COPY
    for (int i = t; i < SH * 40 + SH * 20; i += 256) {
        if (i < SH * 40) {
            int r = i / 40, c4 = i % 40;
            int g = h0 - MU + r;
            int gw = w0 - 8 + 2 * c4;
            float4 v = make_float4(0.f, 0.f, 0.f, 0.f);
            if (g >= 0 && g < HH && gw >= 0 && gw < WW)
                v = *(const float4*)(tb + 2 * ((size_t)g * WW + gw));
            *(float4*)&st[r * (SCW * 2) + 4 * c4] = v;    // 16B-aligned
        } else {
            int j = i - SH * 40;
            int r = j / 20, c4 = j % 20;
            int g = h0 - MU + r;
            int gw = w0 - 8 + 4 * c4;
            float4 v = make_float4(1.f, 1.f, 1.f, 1.f);   // OOB em = exp(0) = 1
            if (g >= 0 && g < HH && gw >= 0 && gw < WW)
                v = *(const float4*)(mb + (size_t)g * WW + gw);
            float* dst = &sm[r * SMS + 4 * c4];
            dst[0] = v.x;
            dst[1] = v.y;
            dst[2] = v.z;
            dst[3] = v.w;
        }
    }
    __syncthreads();

    // ---- shared register window (reused by V then H phase)
    float r0a[21], r1a[21], rea[21];

    // ---- V phase: 240 threads = 80 cols x 3 row-strips {11,11,10}.
    const int c = t % 80;
    const int strip = t / 80;
    const int vr0row = strip * 11;
    const int Rv = (strip == 2) ? 10 : 11;
    if (t < 240) {
        #pragma unroll
        for (int j = 0; j < 21; ++j) {
            if (j < Rv + 10) {
                float2 v = *(const float2*)&st[((vr0row + j) * SCW + c) * 2];
                r0a[j] = v.x; r1a[j] = v.y;
                rea[j] = sm[(vr0row + j) * SMS + c];
            }
        }
    }
    __syncthreads();          // all st reads done; safe to overwrite via sv alias

    __builtin_amdgcn_s_setprio(1);
    if (t < 240) {
        #pragma unroll
        for (int i = 0; i < 11; ++i) {
            if (i < Rv) {
                float tx0 = r0a[i + 5], tx1 = r1a[i + 5];
                float remx = fast_rcp(rea[i + 5]);
                float a0 = 0.f, a1 = 0.f;
                #pragma unroll
                for (int d = 0; d <= 2 * MU; ++d) {
                    float y0 = r0a[i + d], y1 = r1a[i + d], ey = rea[i + d];
                    float s = fast_rcp(fmaf(ey, remx, 1.f));    // (tanh(my-mx)+1)/2
                    float w = s * fmaf(tx0, y0, tx1 * y1);
                    a0 = fmaf(y0, w, a0);
                    a1 = fmaf(y1, w, a1);
                }
                float n2 = fmaf(a0, a0, a1 * a1);
                float inv = (n2 == 0.f) ? 1.f : fast_rsq(n2);
                sv0[(vr0row + i) * SVS + c] = a0 * inv;
                sv1[(vr0row + i) * SVS + c] = a1 * inv;
            }
        }
    }
    __builtin_amdgcn_s_setprio(0);
    __syncthreads();

    // ---- H phase: lane<->row map (r = t&31, colgroup = t>>5 of 8 cols).
    const int r = t & 31;
    const int cg = t >> 5;
    const int cbase = 8 + cg * 8;            // staged col of first center
    #pragma unroll
    for (int j = 0; j < 18; ++j) {
        int sc = cbase - 5 + j;              // 3..76: always in [0,80)
        r0a[j] = sv0[r * SVS + sc];
        r1a[j] = sv1[r * SVS + sc];
        rea[j] = sm[(r + MU) * SMS + sc];
    }
    __syncthreads();          // all sv reads done; safe to overwrite below

    __builtin_amdgcn_s_setprio(1);
    #pragma unroll
    for (int k = 0; k < 8; ++k) {
        float tx0 = r0a[k + 5], tx1 = r1a[k + 5];
        float remx = fast_rcp(rea[k + 5]);
        float a0 = 0.f, a1 = 0.f;
        #pragma unroll
        for (int d = 0; d <= 2 * MU; ++d) {
            float y0 = r0a[k + d], y1 = r1a[k + d], ey = rea[k + d];
            float s = fast_rcp(fmaf(ey, remx, 1.f));
            float w = s * fmaf(tx0, y0, tx1 * y1);
            a0 = fmaf(y0, w, a0);
            a1 = fmaf(y1, w, a1);
        }
        float n2 = fmaf(a0, a0, a1 * a1);
        float inv = (n2 == 0.f) ? 1.f : fast_rsq(n2);
        sv0[r * SVS + cbase + k] = a0 * inv;    // write to LDS (post-barrier)
        sv1[r * SVS + cbase + k] = a1 * inv;
    }
    __builtin_amdgcn_s_setprio(0);
    __syncthreads();

    // ---- coalesced global writeout (lanes along cols)
    #pragma unroll
    for (int m = 0; m < 8; ++m) {
        int px = t + 256 * m;
        int rr = px >> 6, cc = px & 63;
        float v0 = sv0[rr * SVS + 8 + cc];
        float v1 = sv1[rr * SVS + 8 + cc];
        size_t gi = (size_t)(h0 + rr) * WW + (w0 + cc);
        if (PLANAR_OUT) {
            tout[(size_t)(2 * b)     * plane + gi] = v0;
            tout[(size_t)(2 * b + 1) * plane + gi] = v1;
        } else {
            *(float2*)&tout[2 * ((size_t)b * plane + gi)] = make_float2(v0, v1);
        }
    }
}

extern "C" void kernel_launch(void* const* d_in, const int* in_sizes, int n_in,
                              void* d_out, int out_size, void* d_ws, size_t ws_size,
                              hipStream_t stream)
{
    const float* x = (const float*)d_in[0];   // (2,1,1024,1024) fp32
    char* ws = (char*)d_ws;
    const size_t plane = (size_t)HH * WW;

    float* tfA  = (float*)ws;                                           // 16 MB interleaved
    float* tfB  = (float*)(ws + sizeof(float) * BB * 2 * plane);        // 16 MB interleaved
    float* mag  = (float*)(ws + sizeof(float) * BB * 4 * plane);        // 8 MB raw -> em
    float* block_max = (float*)(ws + sizeof(float) * BB * 5 * plane);   // 1024 floats

    sobel_init<<<dim3(4, 128, BB), 256, 0, stream>>>(x, tfA, mag, block_max);

    em_prep<<<dim3(2048), 256, 0, stream>>>(mag, block_max);   // mag -> em in place

    dim3 g(WW / TW, HH / TH, BB);
    etf_vh<0><<<g, 256, 0, stream>>>(tfA, tfB, mag);
    etf_vh<0><<<g, 256, 0, stream>>>(tfB, tfA, mag);
    etf_vh<1><<<g, 256, 0, stream>>>(tfA, (float*)d_out, mag);
}

// Round 10
// 130.883 us; speedup vs baseline: 3.9118x; 1.0140x over previous
//
#include <hip/hip_runtime.h>

#define BB 2
#define HH 1024
#define WW 1024
#define MU 5

// fused-pass tile geometry (exact 131us-proven baseline geometry)
#define TH 32
#define TW 64
#define SH (TH + 2 * MU)   // 42 staged rows
#define SCW 80             // staged cols = TW + 16 (8-col halo each side)
#define SMS 83             // em LDS row stride (odd -> conflict-free H reads)
#define SVS 81             // V-result LDS row stride (odd -> conflict-free H reads)

__device__ __forceinline__ float fast_rcp(float x) { return __builtin_amdgcn_rcpf(x); }
__device__ __forceinline__ float fast_rsq(float x) { return __builtin_amdgcn_rsqf(x); }

// ---------------------------------------------------------------------------
// Kernel 1: Sobel + init tangent (interleaved (B,H,W,2)) + raw mag + block
// max. (Proven baseline version.)
// ---------------------------------------------------------------------------
#define SR 8
__global__ __launch_bounds__(256) void sobel_init(
    const float* __restrict__ x,
    float* __restrict__ tf,          // (B,H,W,2) interleaved
    float* __restrict__ mag,         // (B,H,W) raw
    float* __restrict__ block_max)   // 1024
{
    __shared__ float xs[SR + 2][264];
    const int t = threadIdx.x;
    const int w0 = blockIdx.x * 256;
    const int h0 = blockIdx.y * SR;
    const int b = blockIdx.z;
    const size_t plane = (size_t)HH * WW;
    const float* xb = x + (size_t)b * plane;

    for (int i = t; i < (SR + 2) * 66; i += 256) {
        int r = i / 66, c4 = i % 66;
        int g = h0 - 1 + r;
        int gw = w0 - 4 + 4 * c4;
        float4 v = make_float4(0.f, 0.f, 0.f, 0.f);
        if (g >= 0 && g < HH && gw >= 0 && gw < WW)
            v = *(const float4*)(xb + (size_t)g * WW + gw);
        *(float4*)&xs[r][4 * c4] = v;
    }
    __syncthreads();

    float lmax = 0.f;
    const int c = 4 + t;
    #pragma unroll
    for (int k = 0; k < SR; ++k) {
        const float* rT = xs[k], * rM = xs[k + 1], * rB = xs[k + 2];
        float tl = rT[c - 1], tc = rT[c], tr = rT[c + 1];
        float ml = rM[c - 1],             mr = rM[c + 1];
        float bl = rB[c - 1], bc = rB[c], br = rB[c + 1];
        float s0 = (bl - tl) + 2.f * (bc - tc) + (br - tr);   // k
        float s1 = (tr - tl) + 2.f * (mr - ml) + (br - bl);   // k^T
        float m = sqrtf(fmaf(s0, s0, s1 * s1));
        float inv = (m == 0.f) ? 1.f : fast_rcp(m);
        size_t gi = (size_t)(h0 + k) * WW + (w0 + t);
        mag[(size_t)b * plane + gi] = m;
        ((float2*)tf)[(size_t)b * plane + gi] = make_float2(-s1 * inv, s0 * inv);
        lmax = fmaxf(lmax, m);
    }

    #pragma unroll
    for (int off = 32; off; off >>= 1) lmax = fmaxf(lmax, __shfl_down(lmax, off, 64));
    __shared__ float smax[4];
    if ((t & 63) == 0) smax[t >> 6] = lmax;
    __syncthreads();
    if (t == 0)
        block_max[(blockIdx.z * 128 + blockIdx.y) * 4 + blockIdx.x] =
            fmaxf(fmaxf(smax[0], smax[1]), fmaxf(smax[2], smax[3]));
}

// ---------------------------------------------------------------------------
// Kernel 1.5 (fallback path only, when ws too small for the em buffer):
// gmax reduce + IN-PLACE mag -> em. (R8-proven, 132.7us total.)
// ---------------------------------------------------------------------------
__global__ __launch_bounds__(256) void em_prep(
    float* __restrict__ mag, const float* __restrict__ block_max)
{
    __shared__ float smax[4];
    const int t = threadIdx.x;
    float m = fmaxf(fmaxf(block_max[t], block_max[t + 256]),
                    fmaxf(block_max[t + 512], block_max[t + 768]));
    #pragma unroll
    for (int off = 32; off; off >>= 1) m = fmaxf(m, __shfl_down(m, off, 64));
    if ((t & 63) == 0) smax[t >> 6] = m;
    __syncthreads();
    const float gm = fmaxf(fmaxf(smax[0], smax[1]), fmaxf(smax[2], smax[3]));
    const float s2 = 2.f * fast_rcp(gm);

    const size_t i4 = (size_t)blockIdx.x * 256 + t;   // float4 index
    float4 v = ((const float4*)mag)[i4];
    v.x = __expf(-s2 * v.x);
    v.y = __expf(-s2 * v.y);
    v.z = __expf(-s2 * v.z);
    v.w = __expf(-s2 * v.w);
    ((float4*)mag)[i4] = v;
}

// ---------------------------------------------------------------------------
// Kernel 2: FUSED V+H ETF pass — exact proven compute structure.
// EMPREP=1 (pass 1): msrc = RAW mag; prologue gmax reduce -> s2; stage does
//   em = expf(-s2*mag) exactly as the 131us baseline (R8 evidence: this expf
//   is hidden under stage memory latency); after the stage barrier, writes
//   the block's 32x64 INTERIOR em slice to emw (8 px/thread, drains under
//   the V-read phase -> off critical path). Separate buffer is REQUIRED:
//   in-place would race (block A interior write vs block B halo read).
// EMPREP=0 (passes 2/3): msrc = precomputed em; pure float4 copy-stage
//   (OOB default 1.0 = exp(-0)); no prologue, no expf (R8-proven bits).
// Weight identity: (tanh(my-mx)+1)/2 == 1/(1 + em_y/em_x).
// LDS 40824 B -> 4 blocks/CU.
// ---------------------------------------------------------------------------
template <int PLANAR_OUT, int EMPREP>
__global__ __launch_bounds__(256, 4) void etf_vh(
    const float* __restrict__ tin,   // (B,H,W,2) interleaved
    float* __restrict__ tout,        // interleaved, or planar (B,2,H,W)
    const float* __restrict__ msrc,  // (B,H,W): raw mag (EMPREP) or em
    float* __restrict__ emw,         // (B,H,W) em out (EMPREP only)
    const float* __restrict__ block_max)
{
    __shared__ float lds[SH * SCW * 2 + SH * SMS];   // 40824 B
    __shared__ float smax[4];
    float* st  = lds;                 // staged tang, float2/px, row stride 160 floats
    float* sm  = lds + SH * SCW * 2;  // staged em, row stride SMS
    float* sv0 = lds;                 // V results plane 0 (aliases st)
    float* sv1 = lds + TH * SVS;      // V results plane 1

    const int t = threadIdx.x;

    // XCD-aware swizzle (proven neutral; keeps per-XCD slab L2-resident)
    int lin = blockIdx.x + 16 * blockIdx.y + 512 * blockIdx.z;   // grid 16x32xBB
    lin = (lin & 7) * ((16 * 32 * BB) >> 3) + (lin >> 3);
    const int w0 = (lin & 15) * TW;
    const int h0 = ((lin >> 4) & 31) * TH;
    const int b  = lin >> 9;

    const size_t plane = (size_t)HH * WW;
    const float* tb = tin + 2 * (size_t)b * plane;
    const float* mb = msrc + (size_t)b * plane;

    // ---- prologue (pass 1 only): gmax reduce -> s2
    float s2 = 0.f;
    if (EMPREP) {
        float m = fmaxf(fmaxf(block_max[t], block_max[t + 256]),
                        fmaxf(block_max[t + 512], block_max[t + 768]));
        #pragma unroll
        for (int off = 32; off; off >>= 1) m = fmaxf(m, __shfl_down(m, off, 64));
        if ((t & 63) == 0) smax[t >> 6] = m;
        __syncthreads();
        const float gm = fmaxf(fmaxf(smax[0], smax[1]), fmaxf(smax[2], smax[3]));
        s2 = 2.f * fast_rcp(gm);
    }

    // ---- stage: tang 42x40 float4 (2px); em 42x20 float4 (4px) expf/copy
    for (int i = t; i < SH * 40 + SH * 20; i += 256) {
        if (i < SH * 40) {
            int r = i / 40, c4 = i % 40;
            int g = h0 - MU + r;
            int gw = w0 - 8 + 2 * c4;
            float4 v = make_float4(0.f, 0.f, 0.f, 0.f);
            if (g >= 0 && g < HH && gw >= 0 && gw < WW)
                v = *(const float4*)(tb + 2 * ((size_t)g * WW + gw));
            *(float4*)&st[r * (SCW * 2) + 4 * c4] = v;    // 16B-aligned
        } else {
            int j = i - SH * 40;
            int r = j / 20, c4 = j % 20;
            int g = h0 - MU + r;
            int gw = w0 - 8 + 4 * c4;
            // OOB: raw mag 0 -> expf(-0)=1; copy path default 1.0 directly.
            float4 v = EMPREP ? make_float4(0.f, 0.f, 0.f, 0.f)
                              : make_float4(1.f, 1.f, 1.f, 1.f);
            if (g >= 0 && g < HH && gw >= 0 && gw < WW)
                v = *(const float4*)(mb + (size_t)g * WW + gw);
            float* dst = &sm[r * SMS + 4 * c4];
            if (EMPREP) {
                dst[0] = __expf(-s2 * v.x);
                dst[1] = __expf(-s2 * v.y);
                dst[2] = __expf(-s2 * v.z);
                dst[3] = __expf(-s2 * v.w);
            } else {
                dst[0] = v.x; dst[1] = v.y; dst[2] = v.z; dst[3] = v.w;
            }
        }
    }
    __syncthreads();

    // ---- pass 1: write interior em slice (32x64) to global for passes 2/3.
    // LDS->global, 2 float4/thread; stores drain under the V-read phase.
    if (EMPREP) {
        float* ew = emw + (size_t)b * plane;
        #pragma unroll
        for (int q = 0; q < 2; ++q) {
            int i = t + q * 256;             // 512 float4 chunks = 32 x 16
            int rr = i >> 4, c4 = i & 15;
            const float* s = &sm[(rr + MU) * SMS + 8 + 4 * c4];
            float4 v = make_float4(s[0], s[1], s[2], s[3]);
            *(float4*)&ew[(size_t)(h0 + rr) * WW + (w0 + 4 * c4)] = v;
        }
    }

    // ---- shared register window (reused by V then H phase)
    float r0a[21], r1a[21], rea[21];

    // ---- V phase: 240 threads = 80 cols x 3 row-strips {11,11,10}.
    const int c = t % 80;
    const int strip = t / 80;
    const int vr0row = strip * 11;
    const int Rv = (strip == 2) ? 10 : 11;
    if (t < 240) {
        #pragma unroll
        for (int j = 0; j < 21; ++j) {
            if (j < Rv + 10) {
                float2 v = *(const float2*)&st[((vr0row + j) * SCW + c) * 2];
                r0a[j] = v.x; r1a[j] = v.y;
                rea[j] = sm[(vr0row + j) * SMS + c];
            }
        }
    }
    __syncthreads();          // all st reads done; safe to overwrite via sv alias

    __builtin_amdgcn_s_setprio(1);
    if (t < 240) {
        #pragma unroll
        for (int i = 0; i < 11; ++i) {
            if (i < Rv) {
                float tx0 = r0a[i + 5], tx1 = r1a[i + 5];
                float remx = fast_rcp(rea[i + 5]);
                float a0 = 0.f, a1 = 0.f;
                #pragma unroll
                for (int d = 0; d <= 2 * MU; ++d) {
                    float y0 = r0a[i + d], y1 = r1a[i + d], ey = rea[i + d];
                    float s = fast_rcp(fmaf(ey, remx, 1.f));    // (tanh(my-mx)+1)/2
                    float w = s * fmaf(tx0, y0, tx1 * y1);
                    a0 = fmaf(y0, w, a0);
                    a1 = fmaf(y1, w, a1);
                }
                float n2 = fmaf(a0, a0, a1 * a1);
                float inv = (n2 == 0.f) ? 1.f : fast_rsq(n2);
                sv0[(vr0row + i) * SVS + c] = a0 * inv;
                sv1[(vr0row + i) * SVS + c] = a1 * inv;
            }
        }
    }
    __builtin_amdgcn_s_setprio(0);
    __syncthreads();

    // ---- H phase: lane<->row map (r = t&31, colgroup = t>>5 of 8 cols).
    const int r = t & 31;
    const int cg = t >> 5;
    const int cbase = 8 + cg * 8;            // staged col of first center
    #pragma unroll
    for (int j = 0; j < 18; ++j) {
        int sc = cbase - 5 + j;              // 3..76: always in [0,80)
        r0a[j] = sv0[r * SVS + sc];
        r1a[j] = sv1[r * SVS + sc];
        rea[j] = sm[(r + MU) * SMS + sc];
    }
    __syncthreads();          // all sv reads done; safe to overwrite below

    __builtin_amdgcn_s_setprio(1);
    #pragma unroll
    for (int k = 0; k < 8; ++k) {
        float tx0 = r0a[k + 5], tx1 = r1a[k + 5];
        float remx = fast_rcp(rea[k + 5]);
        float a0 = 0.f, a1 = 0.f;
        #pragma unroll
        for (int d = 0; d <= 2 * MU; ++d) {
            float y0 = r0a[k + d], y1 = r1a[k + d], ey = rea[k + d];
            float s = fast_rcp(fmaf(ey, remx, 1.f));
            float w = s * fmaf(tx0, y0, tx1 * y1);
            a0 = fmaf(y0, w, a0);
            a1 = fmaf(y1, w, a1);
        }
        float n2 = fmaf(a0, a0, a1 * a1);
        float inv = (n2 == 0.f) ? 1.f : fast_rsq(n2);
        sv0[r * SVS + cbase + k] = a0 * inv;    // write to LDS (post-barrier)
        sv1[r * SVS + cbase + k] = a1 * inv;
    }
    __builtin_amdgcn_s_setprio(0);
    __syncthreads();

    // ---- coalesced global writeout (lanes along cols)
    #pragma unroll
    for (int m = 0; m < 8; ++m) {
        int px = t + 256 * m;
        int rr = px >> 6, cc = px & 63;
        float v0 = sv0[rr * SVS + 8 + cc];
        float v1 = sv1[rr * SVS + 8 + cc];
        size_t gi = (size_t)(h0 + rr) * WW + (w0 + cc);
        if (PLANAR_OUT) {
            tout[(size_t)(2 * b)     * plane + gi] = v0;
            tout[(size_t)(2 * b + 1) * plane + gi] = v1;
        } else {
            *(float2*)&tout[2 * ((size_t)b * plane + gi)] = make_float2(v0, v1);
        }
    }
}

extern "C" void kernel_launch(void* const* d_in, const int* in_sizes, int n_in,
                              void* d_out, int out_size, void* d_ws, size_t ws_size,
                              hipStream_t stream)
{
    const float* x = (const float*)d_in[0];   // (2,1,1024,1024) fp32
    char* ws = (char*)d_ws;
    const size_t plane = (size_t)HH * WW;
    const size_t MB = 1u << 20;

    float* tfA  = (float*)ws;                                           // 16 MB interleaved
    float* tfB  = (float*)(ws + sizeof(float) * BB * 2 * plane);        // 16 MB interleaved
    float* mag  = (float*)(ws + sizeof(float) * BB * 4 * plane);        // 8 MB raw
    float* block_max = (float*)(ws + sizeof(float) * BB * 5 * plane);   // 1024 floats
    float* em   = (float*)(ws + 41 * MB);                               // 8 MB em

    sobel_init<<<dim3(4, 128, BB), 256, 0, stream>>>(x, tfA, mag, block_max);

    dim3 g(WW / TW, HH / TH, BB);
    if (ws_size >= 49 * MB) {
        // pass 1 produces em inline; passes 2/3 copy-stage from it
        etf_vh<0, 1><<<g, 256, 0, stream>>>(tfA, tfB, mag, em, block_max);
        etf_vh<0, 0><<<g, 256, 0, stream>>>(tfB, tfA, em, nullptr, nullptr);
        etf_vh<1, 0><<<g, 256, 0, stream>>>(tfA, (float*)d_out, em, nullptr, nullptr);
    } else {
        // R8-proven fallback: em_prep in place, all passes copy-stage
        em_prep<<<dim3(2048), 256, 0, stream>>>(mag, block_max);
        etf_vh<0, 0><<<g, 256, 0, stream>>>(tfA, tfB, mag, nullptr, nullptr);
        etf_vh<0, 0><<<g, 256, 0, stream>>>(tfB, tfA, mag, nullptr, nullptr);
        etf_vh<1, 0><<<g, 256, 0, stream>>>(tfA, (float*)d_out, mag, nullptr, nullptr);
    }
}

// Round 11
// 129.108 us; speedup vs baseline: 3.9656x; 1.0137x over previous
//
#include <hip/hip_runtime.h>

#define BB 2
#define HH 1024
#define WW 1024
#define MU 5

// fused-pass tile geometry (exact 131us-proven baseline geometry)
#define TH 32
#define TW 64
#define SH (TH + 2 * MU)   // 42 staged rows
#define SCW 80             // staged cols = TW + 16 (8-col halo each side)
#define SMS 83             // em LDS row stride (odd -> conflict-free H reads)
#define SVS 81             // V-result LDS row stride (odd -> conflict-free H reads)

__device__ __forceinline__ float fast_rcp(float x) { return __builtin_amdgcn_rcpf(x); }
__device__ __forceinline__ float fast_rsq(float x) { return __builtin_amdgcn_rsqf(x); }

// ---------------------------------------------------------------------------
// Kernel 1: Sobel -> RAW s-field (B,H,W,2) + block max of |s|.
// R10: no normalized-tang write, NO mag write (-8 MB). tang/mag/em are pure
// functions of (s0,s1); pass 1 recomputes them in its stage loop from the
// same bits with the same expressions -> bit-identical. m is still computed
// here (registers only) for the block max — same sqrtf(fmaf(...)) bits.
// ---------------------------------------------------------------------------
#define SR 8
__global__ __launch_bounds__(256) void sobel_init(
    const float* __restrict__ x,
    float* __restrict__ sf,          // (B,H,W,2) interleaved RAW (s0,s1)
    float* __restrict__ block_max)   // 1024
{
    __shared__ float xs[SR + 2][264];
    const int t = threadIdx.x;
    const int w0 = blockIdx.x * 256;
    const int h0 = blockIdx.y * SR;
    const int b = blockIdx.z;
    const size_t plane = (size_t)HH * WW;
    const float* xb = x + (size_t)b * plane;

    for (int i = t; i < (SR + 2) * 66; i += 256) {
        int r = i / 66, c4 = i % 66;
        int g = h0 - 1 + r;
        int gw = w0 - 4 + 4 * c4;
        float4 v = make_float4(0.f, 0.f, 0.f, 0.f);
        if (g >= 0 && g < HH && gw >= 0 && gw < WW)
            v = *(const float4*)(xb + (size_t)g * WW + gw);
        *(float4*)&xs[r][4 * c4] = v;
    }
    __syncthreads();

    float lmax = 0.f;
    const int c = 4 + t;
    #pragma unroll
    for (int k = 0; k < SR; ++k) {
        const float* rT = xs[k], * rM = xs[k + 1], * rB = xs[k + 2];
        float tl = rT[c - 1], tc = rT[c], tr = rT[c + 1];
        float ml = rM[c - 1],             mr = rM[c + 1];
        float bl = rB[c - 1], bc = rB[c], br = rB[c + 1];
        float s0 = (bl - tl) + 2.f * (bc - tc) + (br - tr);   // k
        float s1 = (tr - tl) + 2.f * (mr - ml) + (br - bl);   // k^T
        float m = sqrtf(fmaf(s0, s0, s1 * s1));
        size_t gi = (size_t)(h0 + k) * WW + (w0 + t);
        ((float2*)sf)[(size_t)b * plane + gi] = make_float2(s0, s1);
        lmax = fmaxf(lmax, m);
    }

    #pragma unroll
    for (int off = 32; off; off >>= 1) lmax = fmaxf(lmax, __shfl_down(lmax, off, 64));
    __shared__ float smax[4];
    if ((t & 63) == 0) smax[t >> 6] = lmax;
    __syncthreads();
    if (t == 0)
        block_max[(blockIdx.z * 128 + blockIdx.y) * 4 + blockIdx.x] =
            fmaxf(fmaxf(smax[0], smax[1]), fmaxf(smax[2], smax[3]));
}

// ---------------------------------------------------------------------------
// Kernel 2: FUSED V+H ETF pass — exact proven compute structure.
// EMPREP=1 (pass 1): tin = RAW s-field. Prologue gmax reduce -> s2. MERGED
//   stage loop (1680 iters, was 2520): ONE float4 read (2 px of (s0,s1)) ->
//   m=sqrtf(fmaf(..)), tang=(-s1,s0)*rcp(m) -> st, em=expf(-s2*m) -> sm.
//   Same expressions/bits as old sobel+stage (R7/R8/R9: stage-time
//   transcendentals are hidden under stage memory latency). After the stage
//   barrier: write interior 32x64 em slice to emw for passes 2/3 (R9-proven,
//   drains under V-read). OOB: tang=(0,0), em=1 (exact old semantics).
// EMPREP=0 (passes 2/3): tin = tang ping-pong, msrc = precomputed em; pure
//   float4 copy-stage (OOB default 1.0). R9-proven bits.
// Weight identity: (tanh(my-mx)+1)/2 == 1/(1 + em_y/em_x).
// LDS 40824 B -> 4 blocks/CU.
// ---------------------------------------------------------------------------
template <int PLANAR_OUT, int EMPREP>
__global__ __launch_bounds__(256, 4) void etf_vh(
    const float* __restrict__ tin,   // (B,H,W,2): s-field (pass1) or tang
    float* __restrict__ tout,        // interleaved, or planar (B,2,H,W)
    const float* __restrict__ msrc,  // (B,H,W) precomputed em (passes 2/3)
    float* __restrict__ emw,         // (B,H,W) em out (pass 1)
    const float* __restrict__ block_max)
{
    __shared__ float lds[SH * SCW * 2 + SH * SMS];   // 40824 B
    __shared__ float smax[4];
    float* st  = lds;                 // staged tang, float2/px, row stride 160 floats
    float* sm  = lds + SH * SCW * 2;  // staged em, row stride SMS
    float* sv0 = lds;                 // V results plane 0 (aliases st)
    float* sv1 = lds + TH * SVS;      // V results plane 1

    const int t = threadIdx.x;

    // XCD-aware swizzle (proven neutral; keeps per-XCD slab L2-resident)
    int lin = blockIdx.x + 16 * blockIdx.y + 512 * blockIdx.z;   // grid 16x32xBB
    lin = (lin & 7) * ((16 * 32 * BB) >> 3) + (lin >> 3);
    const int w0 = (lin & 15) * TW;
    const int h0 = ((lin >> 4) & 31) * TH;
    const int b  = lin >> 9;

    const size_t plane = (size_t)HH * WW;
    const float* tb = tin + 2 * (size_t)b * plane;

    // ---- prologue (pass 1 only): gmax reduce -> s2
    float s2 = 0.f;
    if (EMPREP) {
        float m = fmaxf(fmaxf(block_max[t], block_max[t + 256]),
                        fmaxf(block_max[t + 512], block_max[t + 768]));
        #pragma unroll
        for (int off = 32; off; off >>= 1) m = fmaxf(m, __shfl_down(m, off, 64));
        if ((t & 63) == 0) smax[t >> 6] = m;
        __syncthreads();
        const float gm = fmaxf(fmaxf(smax[0], smax[1]), fmaxf(smax[2], smax[3]));
        s2 = 2.f * fast_rcp(gm);
    }

    // ---- stage
    if (EMPREP) {
        // merged: one s-field read -> tang (st) + em (sm), 42x40 chunks
        for (int i = t; i < SH * 40; i += 256) {
            int r = i / 40, c4 = i % 40;
            int g = h0 - MU + r;
            int gw = w0 - 8 + 2 * c4;
            float* td = &st[r * (SCW * 2) + 4 * c4];
            float* ed = &sm[r * SMS + 2 * c4];
            if (g >= 0 && g < HH && gw >= 0 && gw < WW) {
                float4 v = *(const float4*)(tb + 2 * ((size_t)g * WW + gw));
                float m0 = sqrtf(fmaf(v.x, v.x, v.y * v.y));
                float i0 = (m0 == 0.f) ? 1.f : fast_rcp(m0);
                float m1 = sqrtf(fmaf(v.z, v.z, v.w * v.w));
                float i1 = (m1 == 0.f) ? 1.f : fast_rcp(m1);
                *(float4*)td = make_float4(-v.y * i0, v.x * i0, -v.w * i1, v.z * i1);
                ed[0] = __expf(-s2 * m0);
                ed[1] = __expf(-s2 * m1);
            } else {
                *(float4*)td = make_float4(0.f, 0.f, 0.f, 0.f);
                ed[0] = 1.f;
                ed[1] = 1.f;
            }
        }
    } else {
        // tang 42x40 float4 copy; em 42x20 float4 copy from precomputed em
        const float* mb = msrc + (size_t)b * plane;
        for (int i = t; i < SH * 40 + SH * 20; i += 256) {
            if (i < SH * 40) {
                int r = i / 40, c4 = i % 40;
                int g = h0 - MU + r;
                int gw = w0 - 8 + 2 * c4;
                float4 v = make_float4(0.f, 0.f, 0.f, 0.f);
                if (g >= 0 && g < HH && gw >= 0 && gw < WW)
                    v = *(const float4*)(tb + 2 * ((size_t)g * WW + gw));
                *(float4*)&st[r * (SCW * 2) + 4 * c4] = v;    // 16B-aligned
            } else {
                int j = i - SH * 40;
                int r = j / 20, c4 = j % 20;
                int g = h0 - MU + r;
                int gw = w0 - 8 + 4 * c4;
                float4 v = make_float4(1.f, 1.f, 1.f, 1.f);   // OOB em = exp(0) = 1
                if (g >= 0 && g < HH && gw >= 0 && gw < WW)
                    v = *(const float4*)(mb + (size_t)g * WW + gw);
                float* dst = &sm[r * SMS + 4 * c4];
                dst[0] = v.x; dst[1] = v.y; dst[2] = v.z; dst[3] = v.w;
            }
        }
    }
    __syncthreads();

    // ---- pass 1: write interior em slice (32x64) to global for passes 2/3.
    // LDS->global, 2 float4/thread; stores drain under the V-read phase.
    if (EMPREP) {
        float* ew = emw + (size_t)b * plane;
        #pragma unroll
        for (int q = 0; q < 2; ++q) {
            int i = t + q * 256;             // 512 float4 chunks = 32 x 16
            int rr = i >> 4, c4 = i & 15;
            const float* s = &sm[(rr + MU) * SMS + 8 + 4 * c4];
            float4 v = make_float4(s[0], s[1], s[2], s[3]);
            *(float4*)&ew[(size_t)(h0 + rr) * WW + (w0 + 4 * c4)] = v;
        }
    }

    // ---- shared register window (reused by V then H phase)
    float r0a[21], r1a[21], rea[21];

    // ---- V phase: 240 threads = 80 cols x 3 row-strips {11,11,10}.
    const int c = t % 80;
    const int strip = t / 80;
    const int vr0row = strip * 11;
    const int Rv = (strip == 2) ? 10 : 11;
    if (t < 240) {
        #pragma unroll
        for (int j = 0; j < 21; ++j) {
            if (j < Rv + 10) {
                float2 v = *(const float2*)&st[((vr0row + j) * SCW + c) * 2];
                r0a[j] = v.x; r1a[j] = v.y;
                rea[j] = sm[(vr0row + j) * SMS + c];
            }
        }
    }
    __syncthreads();          // all st reads done; safe to overwrite via sv alias

    __builtin_amdgcn_s_setprio(1);
    if (t < 240) {
        #pragma unroll
        for (int i = 0; i < 11; ++i) {
            if (i < Rv) {
                float tx0 = r0a[i + 5], tx1 = r1a[i + 5];
                float remx = fast_rcp(rea[i + 5]);
                float a0 = 0.f, a1 = 0.f;
                #pragma unroll
                for (int d = 0; d <= 2 * MU; ++d) {
                    float y0 = r0a[i + d], y1 = r1a[i + d], ey = rea[i + d];
                    float s = fast_rcp(fmaf(ey, remx, 1.f));    // (tanh(my-mx)+1)/2
                    float w = s * fmaf(tx0, y0, tx1 * y1);
                    a0 = fmaf(y0, w, a0);
                    a1 = fmaf(y1, w, a1);
                }
                float n2 = fmaf(a0, a0, a1 * a1);
                float inv = (n2 == 0.f) ? 1.f : fast_rsq(n2);
                sv0[(vr0row + i) * SVS + c] = a0 * inv;
                sv1[(vr0row + i) * SVS + c] = a1 * inv;
            }
        }
    }
    __builtin_amdgcn_s_setprio(0);
    __syncthreads();

    // ---- H phase: lane<->row map (r = t&31, colgroup = t>>5 of 8 cols).
    const int r = t & 31;
    const int cg = t >> 5;
    const int cbase = 8 + cg * 8;            // staged col of first center
    #pragma unroll
    for (int j = 0; j < 18; ++j) {
        int sc = cbase - 5 + j;              // 3..76: always in [0,80)
        r0a[j] = sv0[r * SVS + sc];
        r1a[j] = sv1[r * SVS + sc];
        rea[j] = sm[(r + MU) * SMS + sc];
    }
    __syncthreads();          // all sv reads done; safe to overwrite below

    __builtin_amdgcn_s_setprio(1);
    #pragma unroll
    for (int k = 0; k < 8; ++k) {
        float tx0 = r0a[k + 5], tx1 = r1a[k + 5];
        float remx = fast_rcp(rea[k + 5]);
        float a0 = 0.f, a1 = 0.f;
        #pragma unroll
        for (int d = 0; d <= 2 * MU; ++d) {
            float y0 = r0a[k + d], y1 = r1a[k + d], ey = rea[k + d];
            float s = fast_rcp(fmaf(ey, remx, 1.f));
            float w = s * fmaf(tx0, y0, tx1 * y1);
            a0 = fmaf(y0, w, a0);
            a1 = fmaf(y1, w, a1);
        }
        float n2 = fmaf(a0, a0, a1 * a1);
        float inv = (n2 == 0.f) ? 1.f : fast_rsq(n2);
        sv0[r * SVS + cbase + k] = a0 * inv;    // write to LDS (post-barrier)
        sv1[r * SVS + cbase + k] = a1 * inv;
    }
    __builtin_amdgcn_s_setprio(0);
    __syncthreads();

    // ---- coalesced global writeout (lanes along cols)
    #pragma unroll
    for (int m = 0; m < 8; ++m) {
        int px = t + 256 * m;
        int rr = px >> 6, cc = px & 63;
        float v0 = sv0[rr * SVS + 8 + cc];
        float v1 = sv1[rr * SVS + 8 + cc];
        size_t gi = (size_t)(h0 + rr) * WW + (w0 + cc);
        if (PLANAR_OUT) {
            tout[(size_t)(2 * b)     * plane + gi] = v0;
            tout[(size_t)(2 * b + 1) * plane + gi] = v1;
        } else {
            *(float2*)&tout[2 * ((size_t)b * plane + gi)] = make_float2(v0, v1);
        }
    }
}

extern "C" void kernel_launch(void* const* d_in, const int* in_sizes, int n_in,
                              void* d_out, int out_size, void* d_ws, size_t ws_size,
                              hipStream_t stream)
{
    const float* x = (const float*)d_in[0];   // (2,1,1024,1024) fp32
    char* ws = (char*)d_ws;
    const size_t plane = (size_t)HH * WW;

    float* tfA  = (float*)ws;                                           // 16 MB: s-field, then tang
    float* tfB  = (float*)(ws + sizeof(float) * BB * 2 * plane);        // 16 MB tang ping-pong
    float* em   = (float*)(ws + sizeof(float) * BB * 4 * plane);        // 8 MB em (old mag slot)
    float* block_max = (float*)(ws + sizeof(float) * BB * 5 * plane);   // 1024 floats

    sobel_init<<<dim3(4, 128, BB), 256, 0, stream>>>(x, tfA, block_max);

    dim3 g(WW / TW, HH / TH, BB);
    // pass 1: s-field -> tang+em inline; passes 2/3 copy-stage from em
    etf_vh<0, 1><<<g, 256, 0, stream>>>(tfA, tfB, nullptr, em, block_max);
    etf_vh<0, 0><<<g, 256, 0, stream>>>(tfB, tfA, em, nullptr, nullptr);
    etf_vh<1, 0><<<g, 256, 0, stream>>>(tfA, (float*)d_out, em, nullptr, nullptr);
}